// Round 8
// baseline (371.739 us; speedup 1.0000x reference)
//
#include <hip/hip_runtime.h>

typedef __attribute__((ext_vector_type(8))) __bf16 bfx8;
typedef __attribute__((ext_vector_type(4))) float f32x4;

__device__ __forceinline__ float s2f(unsigned short s) {
  return __uint_as_float((unsigned int)s << 16);
}
// round-half-up bf16 convert (2 VALU ops; tie-only difference vs RNE)
__device__ __forceinline__ unsigned short f2s(float f) {
  return (unsigned short)((__float_as_uint(f) + 0x8000u) >> 16);
}

// ---------------------------------------------------------------------------
// Async MFMA GEMM core (global_load_lds staging, XOR-swizzled; R5-verified:
// SQ_LDS_BANK_CONFLICT == 0). Both operands [row][k] k-contiguous.
// D[m][n] = sum_k Ag[m][k]*Bg[n][k]. 256 thr = 4 waves 2x2.
// ---------------------------------------------------------------------------
template<int BM, int BN, int BK>
__device__ __forceinline__ void gemm_core_async(
    const unsigned short* __restrict__ Ag, int lda,
    const unsigned short* __restrict__ Bg, int ldb, int K,
    unsigned short* As, unsigned short* Bs, f32x4* acc)
{
  static_assert(BK == 64, "BK must be 64 (128B rows)");
  constexpr int WM = BM / 2, WN = BN / 2;
  constexpr int MT = WM / 16, NT = WN / 16;
  constexpr int SA = BM / 8, SB = BN / 8;   // 1024B segments per tile
  const int tid = threadIdx.x;
  const int lane = tid & 63, wave = tid >> 6;
  const int lr = lane & 15, quad = lane >> 4;
  const int sw = lr & 7;
  const int rl = lane >> 3;                  // row within segment (0..7)
  const int vg = (lane & 7) ^ rl;            // swizzled global vec index
  const int wm = (wave >> 1) * WM, wn = (wave & 1) * WN;

  for (int k0 = 0; k0 < K; k0 += BK) {
#pragma unroll
    for (int s = wave; s < SA; s += 4) {
      const unsigned short* g = Ag + (size_t)(s * 8 + rl) * lda + k0 + vg * 8;
      __builtin_amdgcn_global_load_lds(
          (__attribute__((address_space(1))) void*)g,
          (__attribute__((address_space(3))) void*)(As + s * 512), 16, 0, 0);
    }
#pragma unroll
    for (int s = wave; s < SB; s += 4) {
      const unsigned short* g = Bg + (size_t)(s * 8 + rl) * ldb + k0 + vg * 8;
      __builtin_amdgcn_global_load_lds(
          (__attribute__((address_space(1))) void*)g,
          (__attribute__((address_space(3))) void*)(Bs + s * 512), 16, 0, 0);
    }
    __syncthreads();
#pragma unroll
    for (int kk = 0; kk < BK; kk += 32) {
      const int kv = kk >> 3;                // 0 or 4
      bfx8 af[MT], bfr[NT];
#pragma unroll
      for (int i = 0; i < MT; ++i)
        af[i] = *(const bfx8*)(As + (wm + i * 16 + lr) * BK
                               + (((quad + kv) ^ sw) << 3));
#pragma unroll
      for (int j = 0; j < NT; ++j)
        bfr[j] = *(const bfx8*)(Bs + (wn + j * 16 + lr) * BK
                                + (((quad + kv) ^ sw) << 3));
#pragma unroll
      for (int i = 0; i < MT; ++i)
#pragma unroll
        for (int j = 0; j < NT; ++j)
          acc[i * NT + j] = __builtin_amdgcn_mfma_f32_16x16x32_bf16(
              af[i], bfr[j], acc[i * NT + j], 0, 0, 0);
    }
    __syncthreads();
  }
}

// ---------------------------------------------------------------------------
// k_pre: fused x transpose (fp32 [4][512][4096] -> bf16 x_t [4][4096][512],
// blocks 0..2047) and weight converts (blocks 2048..3071).
// ---------------------------------------------------------------------------
__global__ __launch_bounds__(256) void k_pre(
    const float* __restrict__ x, unsigned short* __restrict__ xt,
    const float* __restrict__ wq, const float* __restrict__ wk,
    const float* __restrict__ wv, const float* __restrict__ wW,
    unsigned short* __restrict__ wqk, unsigned short* __restrict__ wvb,
    unsigned short* __restrict__ wWb)
{
  const int bid = blockIdx.x, tid = threadIdx.x;
  if (bid < 2048) {
    __shared__ float t[64][65];
    const int b = bid >> 9, c0 = ((bid >> 6) & 7) * 64, n0 = (bid & 63) * 64;
    const float* xb = x + ((size_t)b << 21);
    const int hi = tid >> 6, lo = tid & 63;
#pragma unroll
    for (int p = 0; p < 16; ++p)
      t[hi + p * 4][lo] = xb[(size_t)(c0 + hi + p * 4) * 4096 + n0 + lo];
    __syncthreads();
    unsigned short* xtb = xt + ((size_t)b << 21);
#pragma unroll
    for (int p = 0; p < 16; ++p)
      xtb[(size_t)(n0 + hi + p * 4) * 512 + c0 + lo] = f2s(t[lo][hi + p * 4]);
  } else {
    int i = (bid - 2048) * 256 + tid;              // i < 262144
    wqk[i] = f2s(i < 131072 ? wq[i] : wk[i - 131072]);
    if (i < 131072) { wvb[i] = f2s(wv[i]); wWb[i] = f2s(wW[i]); }
  }
}

// ---------------------------------------------------------------------------
// k_qkv: fused QK GEMM (+fp32 BN stats partials in epilogue) and V GEMM.
// ---------------------------------------------------------------------------
__global__ __launch_bounds__(256) void k_qkv(
    const unsigned short* __restrict__ xt, const unsigned short* __restrict__ wqk,
    const unsigned short* __restrict__ wvb, const float* __restrict__ bv,
    unsigned short* __restrict__ zt, unsigned short* __restrict__ v,
    float* __restrict__ stat)
{
  __shared__ __align__(16) unsigned short As[128 * 64], Bs[128 * 64];
  f32x4 acc[16] = {};
  const int b = blockIdx.z, n0 = blockIdx.x * 128, t = blockIdx.y;
  const int lane = threadIdx.x & 63, wave = threadIdx.x >> 6;
  const int lr = lane & 15, quad = lane >> 4;
  const int wm = (wave >> 1) * 64, wn = (wave & 1) * 64;

  if (t < 4) {
    const int o0 = t * 128;
    gemm_core_async<128, 128, 64>(xt + ((size_t)b * 4096 + n0) * 512, 512,
                                  wqk + (size_t)o0 * 512, 512, 512, As, Bs, acc);
    float s[4] = {}, ss[4] = {};
#pragma unroll
    for (int i = 0; i < 4; ++i)
#pragma unroll
      for (int j = 0; j < 4; ++j)
#pragma unroll
        for (int r = 0; r < 4; ++r) {
          float a = acc[i * 4 + j][r];
          int row = wm + i * 16 + quad * 4 + r, col = wn + j * 16 + lr;
          zt[((size_t)b * 4096 + n0 + row) * 512 + o0 + col] = f2s(a);
          s[j] += a; ss[j] += a * a;
        }
#pragma unroll
    for (int j = 0; j < 4; ++j) {
      s[j]  += __shfl_down(s[j], 32, 64);  s[j]  += __shfl_down(s[j], 16, 64);
      ss[j] += __shfl_down(ss[j], 32, 64); ss[j] += __shfl_down(ss[j], 16, 64);
      if (quad == 0) {
        int o = o0 + wn + j * 16 + lr;
        atomicAdd(&stat[o * 2], s[j]);
        atomicAdd(&stat[o * 2 + 1], ss[j]);
      }
    }
  } else {
    const int cv0 = (t - 4) * 128;
    gemm_core_async<128, 128, 64>(wvb + (size_t)cv0 * 512, 512,
                                  xt + ((size_t)b * 4096 + n0) * 512, 512, 512,
                                  As, Bs, acc);
#pragma unroll
    for (int i = 0; i < 4; ++i)
#pragma unroll
      for (int j = 0; j < 4; ++j)
#pragma unroll
        for (int r = 0; r < 4; ++r) {
          int row = wm + i * 16 + quad * 4 + r, col = wn + j * 16 + lr;
          v[((size_t)b * 256 + cv0 + row) * 4096 + n0 + col] =
              f2s(acc[i * 4 + j][r] + bv[cv0 + row]);
        }
  }
}

// ---------------------------------------------------------------------------
// BN+ReLU: q_t[n][c] / k_t[n][c] bf16 from z_t columns.
// ---------------------------------------------------------------------------
__global__ __launch_bounds__(256) void k_bnrelu(
    const unsigned short* __restrict__ zt, const float* __restrict__ stats_raw,
    const float* __restrict__ gq, const float* __restrict__ betaq,
    const float* __restrict__ gk, const float* __restrict__ betak,
    unsigned short* __restrict__ qt, unsigned short* __restrict__ kt)
{
  const int t = threadIdx.x;
  const float mA = stats_raw[t * 2] * (1.f / 16384.f);
  const float vA = stats_raw[t * 2 + 1] * (1.f / 16384.f) - mA * mA;
  const float scA = rsqrtf(vA + 1e-5f) * gq[t], beA = betaq[t];
  const float mB = stats_raw[(t + 256) * 2] * (1.f / 16384.f);
  const float vB = stats_raw[(t + 256) * 2 + 1] * (1.f / 16384.f) - mB * mB;
  const float scB = rsqrtf(vB + 1e-5f) * gk[t], beB = betak[t];
  const int r0 = blockIdx.x * 64;
  for (int r = r0; r < r0 + 64; ++r) {
    float a = s2f(zt[(size_t)r * 512 + t]);
    qt[(size_t)r * 256 + t] = f2s(fmaxf((a - mA) * scA + beA, 0.f));
    float c = s2f(zt[(size_t)r * 512 + t + 256]);
    kt[(size_t)r * 256 + t] = f2s(fmaxf((c - mB) * scB + beB, 0.f));
  }
}

// ---------------------------------------------------------------------------
// k_att: fused flash-style attention. P never hits global memory.
// Per block: batch b, n-tile 64 (S rows), all 256 c. Fixed-shift softmax
// (q,k>=0 -> s>=0; exp(s/16-20) safe) -> NO online rescaling: just accumulate
// ctx[n][c] += exp(S)*v over m-chunks + row sums l[n]; divide at the end.
//
// LDS: kt tile 32K (persistent) + qt chunk 32K + v chunk 32K + P_s 9K + lrow.
// Wide-row (512B) staging swizzle: slot = vec ^ (row&7); read slot
// (quad+kv)^(lr&7) -> 8 bank groups x 2 rows = 2-way (free).
// P_s: written from QK C/D layout (row=quad*4+r, col=lr), read as PV A-frags
// (row=lr, k=quad*8+j), pad stride 72 halves.
// ---------------------------------------------------------------------------
__global__ __launch_bounds__(256) void k_att(
    const unsigned short* __restrict__ qt, const unsigned short* __restrict__ kt,
    const unsigned short* __restrict__ vglob, unsigned short* __restrict__ ctx)
{
  __shared__ __align__(16) unsigned short kt_s[64 * 256];
  __shared__ __align__(16) unsigned short qt_s[64 * 256];
  __shared__ __align__(16) unsigned short v_s[256 * 64];
  __shared__ __align__(16) unsigned short P_s[64 * 72];
  __shared__ float lrow[64];

  const int b = blockIdx.y, n0 = blockIdx.x * 64;
  const int tid = threadIdx.x, lane = tid & 63, wave = tid >> 6;
  const int lr = lane & 15, quad = lane >> 4;
  const int sw = lr & 7;
  const int wns = (wave >> 1) * 32;      // n-half (S rows / ctx rows)
  const int wnm = (wave & 1) * 32;       // m-half in QK
  const int wnc = (wave & 1) * 128;      // c-half in PV

  const unsigned short* KT = kt + ((size_t)b * 4096 + n0) * 256;
  const unsigned short* QT = qt + (size_t)b * 4096 * 256;
  const unsigned short* V  = vglob + (size_t)b * 256 * 4096;

  const int rl2 = lane >> 5, sl32 = lane & 31;                 // wide rows
  const int rl8 = lane >> 3, vg8 = (lane & 7) ^ (lane >> 3);   // narrow rows

  if (tid < 64) lrow[tid] = 0.f;

  // prologue: kt (persistent) + qt chunk 0 + v chunk 0
#pragma unroll
  for (int s = wave; s < 32; s += 4) {
    int row = 2 * s + rl2;
    __builtin_amdgcn_global_load_lds(
        (__attribute__((address_space(1))) void*)(KT + (size_t)row * 256 + ((sl32 ^ (row & 7)) << 3)),
        (__attribute__((address_space(3))) void*)(kt_s + s * 512), 16, 0, 0);
  }
#pragma unroll
  for (int s = wave; s < 32; s += 4) {
    int row = 2 * s + rl2;
    __builtin_amdgcn_global_load_lds(
        (__attribute__((address_space(1))) void*)(QT + (size_t)row * 256 + ((sl32 ^ (row & 7)) << 3)),
        (__attribute__((address_space(3))) void*)(qt_s + s * 512), 16, 0, 0);
  }
#pragma unroll
  for (int s = wave; s < 32; s += 4) {
    int c = s * 8 + rl8;
    __builtin_amdgcn_global_load_lds(
        (__attribute__((address_space(1))) void*)(V + (size_t)c * 4096 + (vg8 << 3)),
        (__attribute__((address_space(3))) void*)(v_s + s * 512), 16, 0, 0);
  }

  f32x4 acc_o[16] = {};
  const float C1 = 0.0625f * 1.44269504f;    // log2(e)/16
  const float C0 = -20.0f * 1.44269504f;     // -20*log2(e)

  for (int mc = 0; mc < 64; ++mc) {
    __syncthreads();                    // A: qt/v chunk ready; P_s free
    // ---- QK: S[64n][64m], K=256 ----
    f32x4 accs[4] = {};
#pragma unroll
    for (int kv = 0; kv < 32; kv += 4) {
      bfx8 ak[2], bq[2];
#pragma unroll
      for (int i = 0; i < 2; ++i)
        ak[i] = *(const bfx8*)(kt_s + (wns + i * 16 + lr) * 256
                               + (((quad + kv) ^ sw) << 3));
#pragma unroll
      for (int j = 0; j < 2; ++j)
        bq[j] = *(const bfx8*)(qt_s + (wnm + j * 16 + lr) * 256
                               + (((quad + kv) ^ sw) << 3));
#pragma unroll
      for (int i = 0; i < 2; ++i)
#pragma unroll
        for (int j = 0; j < 2; ++j)
          accs[i * 2 + j] = __builtin_amdgcn_mfma_f32_16x16x32_bf16(
              ak[i], bq[j], accs[i * 2 + j], 0, 0, 0);
    }
    // ---- exp epilogue -> P_s (bf16) + row-sum atomics ----
#pragma unroll
    for (int i = 0; i < 2; ++i)
#pragma unroll
      for (int r = 0; r < 4; ++r) {
        int row = wns + i * 16 + quad * 4 + r;
        float rs = 0.f;
#pragma unroll
        for (int j = 0; j < 2; ++j) {
          float p = __builtin_amdgcn_exp2f(fmaf(accs[i * 2 + j][r], C1, C0));
          P_s[row * 72 + wnm + j * 16 + lr] = f2s(p);
          rs += p;
        }
        rs += __shfl_down(rs, 8, 16);
        rs += __shfl_down(rs, 4, 16);
        rs += __shfl_down(rs, 2, 16);
        rs += __shfl_down(rs, 1, 16);
        if (lr == 0) atomicAdd(&lrow[row], rs);
      }
    __syncthreads();                    // B: P_s ready; qt consumed
    // prefetch next qt chunk (overlaps PV compute)
    if (mc + 1 < 64) {
      const unsigned short* Qn = QT + (size_t)(mc + 1) * 64 * 256;
#pragma unroll
      for (int s = wave; s < 32; s += 4) {
        int row = 2 * s + rl2;
        __builtin_amdgcn_global_load_lds(
            (__attribute__((address_space(1))) void*)(Qn + (size_t)row * 256 + ((sl32 ^ (row & 7)) << 3)),
            (__attribute__((address_space(3))) void*)(qt_s + s * 512), 16, 0, 0);
      }
    }
    // ---- PV: ctx[64n][256c] += P_s * v_s, K=64 ----
#pragma unroll
    for (int kv = 0; kv < 8; kv += 4) {   // k chunk = kv*8 in {0,32}
      bfx8 ap[2], bv_[8];
#pragma unroll
      for (int i = 0; i < 2; ++i)
        ap[i] = *(const bfx8*)(P_s + (wns + i * 16 + lr) * 72 + (kv + quad) * 8);
#pragma unroll
      for (int j = 0; j < 8; ++j)
        bv_[j] = *(const bfx8*)(v_s + (wnc + j * 16 + lr) * 64
                                + (((quad + kv) ^ sw) << 3));
#pragma unroll
      for (int i = 0; i < 2; ++i)
#pragma unroll
        for (int j = 0; j < 8; ++j)
          acc_o[i * 8 + j] = __builtin_amdgcn_mfma_f32_16x16x32_bf16(
              ap[i], bv_[j], acc_o[i * 8 + j], 0, 0, 0);
    }
    __syncthreads();                    // C: v consumed
    if (mc + 1 < 64) {
      const unsigned short* Vn = V + (size_t)(mc + 1) * 64;
#pragma unroll
      for (int s = wave; s < 32; s += 4) {
        int c = s * 8 + rl8;
        __builtin_amdgcn_global_load_lds(
            (__attribute__((address_space(1))) void*)(Vn + (size_t)c * 4096 + (vg8 << 3)),
            (__attribute__((address_space(3))) void*)(v_s + s * 512), 16, 0, 0);
      }
    }
  }
  // ---- finalize: divide by row sums, store ctx bf16 ----
#pragma unroll
  for (int i = 0; i < 2; ++i)
#pragma unroll
    for (int r = 0; r < 4; ++r) {
      int n = wns + i * 16 + quad * 4 + r;
      float linv = 1.f / lrow[n];
#pragma unroll
      for (int j = 0; j < 8; ++j)
        ctx[((size_t)b * 4096 + n0 + n) * 256 + wnc + j * 16 + lr] =
            f2s(acc_o[i * 8 + j][r] * linv);
    }
}

// ---------------------------------------------------------------------------
// Out: out[b][o][n] = sum_cv wW[o][cv] ctx[b,n][cv] + bW[o] + x[b][o][n]
// ---------------------------------------------------------------------------
__global__ __launch_bounds__(256) void k_out(
    const unsigned short* __restrict__ wWb, const float* __restrict__ bW,
    const unsigned short* __restrict__ ctx, const float* __restrict__ x,
    float* __restrict__ out)
{
  __shared__ __align__(16) unsigned short As[128 * 64], Bs[128 * 64];
  f32x4 acc[16] = {};
  const int b = blockIdx.z, n0 = blockIdx.x * 128, o0 = blockIdx.y * 128;
  gemm_core_async<128, 128, 64>(wWb + (size_t)o0 * 256, 256,
                                ctx + ((size_t)b * 4096 + n0) * 256, 256, 256,
                                As, Bs, acc);
  const int lane = threadIdx.x & 63, wave = threadIdx.x >> 6;
  const int lr = lane & 15, quad = lane >> 4;
  const int wm = (wave >> 1) * 64, wn = (wave & 1) * 64;
#pragma unroll
  for (int i = 0; i < 4; ++i)
#pragma unroll
    for (int j = 0; j < 4; ++j)
#pragma unroll
      for (int r = 0; r < 4; ++r) {
        int row = wm + i * 16 + quad * 4 + r, col = wn + j * 16 + lr;
        size_t idx = ((size_t)b * 512 + o0 + row) * 4096 + n0 + col;
        out[idx] = acc[i * 4 + j][r] + bW[o0 + row] + x[idx];
      }
}

// ---------------------------------------------------------------------------
extern "C" void kernel_launch(void* const* d_in, const int* in_sizes, int n_in,
                              void* d_out, int out_size, void* d_ws, size_t ws_size,
                              hipStream_t stream)
{
  const float* x     = (const float*)d_in[0];
  const float* wq    = (const float*)d_in[1];
  // d_in[2] = bq: cancelled exactly by BN mean-subtraction
  const float* gq    = (const float*)d_in[3];
  const float* betaq = (const float*)d_in[4];
  const float* wk    = (const float*)d_in[5];
  // d_in[6] = bk: cancelled
  const float* gk    = (const float*)d_in[7];
  const float* betak = (const float*)d_in[8];
  const float* wv    = (const float*)d_in[9];
  const float* bv    = (const float*)d_in[10];
  const float* wW    = (const float*)d_in[11];
  const float* bW    = (const float*)d_in[12];
  float* out = (float*)d_out;

  // workspace layout (ws_size = 256 MiB; P/opart eliminated by k_att fusion)
  char* ws = (char*)d_ws;
  unsigned short* qt   = (unsigned short*)(ws);              //  8 MiB [4*4096,256]
  unsigned short* kt   = (unsigned short*)(ws + 8388608);    //  8 MiB
  unsigned short* v    = (unsigned short*)(ws + 16777216);   //  8 MiB [4,256,4096]
  unsigned short* ctx  = (unsigned short*)(ws + 25165824);   //  8 MiB [4*4096,256]
  unsigned short* wqk  = (unsigned short*)(ws + 33554432);   // 512 KiB [512,512]
  unsigned short* wvb  = (unsigned short*)(ws + 34078720);   // 256 KiB [256,512]
  unsigned short* wWb  = (unsigned short*)(ws + 34340864);   // 256 KiB [512,256]
  float*          stat = (float*)         (ws + 34603008);   //   4 KiB
  unsigned short* xt   = (unsigned short*)(ws + 35651584);   // 16 MiB
  unsigned short* zt   = (unsigned short*)(ws + 52428800);   // 16 MiB

  (void)hipMemsetAsync(stat, 0, 4096, stream);
  k_pre   <<<3072, 256, 0, stream>>>(x, xt, wq, wk, wv, wW, wqk, wvb, wWb);
  k_qkv   <<<dim3(32, 6, 4), 256, 0, stream>>>(xt, wqk, wvb, bv, zt, v, stat);
  k_bnrelu<<<256, 256, 0, stream>>>(zt, stat, gq, betaq, gk, betak, qt, kt);
  k_att   <<<dim3(64, 4), 256, 0, stream>>>(qt, kt, v, ctx);
  k_out   <<<dim3(32, 4, 4), 256, 0, stream>>>(wWb, bW, ctx, x, out);
}